// Round 6
// baseline (200.703 us; speedup 1.0000x reference)
//
#include <hip/hip_runtime.h>

// Problem constants (fixed by setup_inputs in the reference)
#define S_SPK 2
#define B_BATCH 4
#define M_MIC 4
#define W_TAP 3
#define F_FREQ 257
#define T_TIME 512
#define C_CH 4
#define FT (F_FREQ * T_TIME)      // 131584

#define NBLK_X 65                 // ceil(F/4): 4 f per block, 1 per wave
#define NBLK_Y 32                 // S*B*4 t-quarters
#define NSLOT (NBLK_X * NBLK_Y)   // 2080 partial slots

// 4-byte-aligned vector types: mix window loads are only dword-aligned.
typedef float float4u __attribute__((ext_vector_type(4), aligned(4)));
typedef float float2a __attribute__((ext_vector_type(2), aligned(8)));

#define AS1 __attribute__((address_space(1)))
#define AS3 __attribute__((address_space(3)))

// ws layout: float partial[NSLOT][2]  (slot = by*NBLK_X + bx; [0]=L0, [1]=L1)
//
// Round-5 lesson: VGPR-held load batching is compiler-limited (it re-groups
// loads into small load->waitcnt->consume clusters). The mask stream (101 of
// 152 MB) is therefore staged via global_load_lds_dwordx4: zero result VGPRs,
// so a wave puts its whole 12 KB mask tile in flight in 12 instructions.
// Per-wave private LDS region -> no barrier, just one vmcnt(0).

__global__ __launch_bounds__(256) void pit_main_kernel(
    const float* __restrict__ masks,   // [S,B,M,W,F,T,2]
    const float* __restrict__ mixr,    // [S,B,M,F,T]
    const float* __restrict__ mixi,    // [S,B,M,F,T]
    const float* __restrict__ tgtr,    // [S,B,C,F,T] (use c=0)
    const float* __restrict__ tgti,    // [S,B,C,F,T]
    float* __restrict__ ws)
{
    const int sb   = blockIdx.y >> 2;       // so*B + b
    const int tq   = blockIdx.y & 3;        // t-quarter
    const int b    = sb & 3;
    const int wave = threadIdx.x >> 6;
    const int lane = threadIdx.x & 63;

    const int f    = blockIdx.x * 4 + wave; // one f-row per wave
    const int fc   = (f < F_FREQ) ? f : (F_FREQ - 1);   // clamped (no OOB)
    const float vf = (f < F_FREQ) ? 1.0f : 0.0f;        // validity flag

    const int t0 = tq * 128 + (lane << 1);
    const long rowBase = (long)fc * T_TIME;
    const long mixSB   = (long)sb * M_MIC * FT + rowBase;
    const long mskSB   = (long)sb * M_MIC;

    // [wave][m*3+w][256 floats]: 1 KB per (m,w) row = 128 t x (re,im). 48 KB.
    __shared__ float lmask[4][M_MIC * W_TAP][256];

    // ---- stage all 12 mask rows to LDS: zero VGPR results, all in flight ----
    // src per lane: 16 B at t = tq*128 + 2*lane; dest wave-uniform, lane*16.
    #pragma unroll
    for (int m = 0; m < M_MIC; ++m) {
        #pragma unroll
        for (int w = 0; w < W_TAP; ++w) {
            const float* srow = masks +
                ((((mskSB + m) * W_TAP + w) * F_FREQ + fc) * (long)T_TIME + tq * 128) * 2
                + (lane << 2);
            __builtin_amdgcn_global_load_lds(
                (const AS1 void*)srow,
                (AS3 void*)&lmask[wave][m * W_TAP + w][0],
                16, 0, 0);
        }
    }

    // ---- mix window register loads: wv[m][k] = mix[m][f][tc+k], k=0..3 ----
    int tc = t0 - 1;
    tc = tc < 0 ? 0 : tc;
    tc = tc > (T_TIME - 4) ? (T_TIME - 4) : tc;

    float4u wr[M_MIC], wi[M_MIC];
    #pragma unroll
    for (int m = 0; m < M_MIC; ++m) {
        wr[m] = *(const float4u*)(mixr + mixSB + (long)m * FT + tc);
        wi[m] = *(const float4u*)(mixi + mixSB + (long)m * FT + tc);
    }

    // ---- target loads (channel 0), both candidate speakers ----
    const long tOff = rowBase + t0;
    const float2a t0r = *(const float2a*)(tgtr + ((long)(0 * B_BATCH + b) * C_CH) * FT + tOff);
    const float2a t0i = *(const float2a*)(tgti + ((long)(0 * B_BATCH + b) * C_CH) * FT + tOff);
    const float2a t1r = *(const float2a*)(tgtr + ((long)(1 * B_BATCH + b) * C_CH) * FT + tOff);
    const float2a t1i = *(const float2a*)(tgti + ((long)(1 * B_BATCH + b) * C_CH) * FT + tOff);

    // ---- boundary fixup on window registers (after all loads issued) ----
    if (t0 == 0) {                 // loaded [0..3], want [pad,0,1,2]
        #pragma unroll
        for (int m = 0; m < M_MIC; ++m) {
            wr[m][3] = wr[m][2]; wr[m][2] = wr[m][1]; wr[m][1] = wr[m][0]; wr[m][0] = 0.0f;
            wi[m][3] = wi[m][2]; wi[m][2] = wi[m][1]; wi[m][1] = wi[m][0]; wi[m][0] = 0.0f;
        }
    } else if (t0 == T_TIME - 2) { // loaded [508..511], want [509,510,511,pad]
        #pragma unroll
        for (int m = 0; m < M_MIC; ++m) {
            wr[m][0] = wr[m][1]; wr[m][1] = wr[m][2]; wr[m][2] = wr[m][3]; wr[m][3] = 0.0f;
            wi[m][0] = wi[m][1]; wi[m][1] = wi[m][2]; wi[m][2] = wi[m][3]; wi[m][3] = 0.0f;
        }
    }

    // ---- wait for the LDS-staged masks (and remaining reg loads) ----
    asm volatile("s_waitcnt vmcnt(0)" ::: "memory");

    // ---- complex MAC over (m,w), masks consumed from LDS (ds_read_b128) ----
    float or0 = 0.f, oi0 = 0.f, or1 = 0.f, oi1 = 0.f;
    #pragma unroll
    for (int m = 0; m < M_MIC; ++m) {
        #pragma unroll
        for (int w = 0; w < W_TAP; ++w) {
            const float4 qq = *(const float4*)&lmask[wave][m * W_TAP + w][lane << 2];
            or0 += wr[m][w]     * qq.x - wi[m][w]     * qq.y;
            oi0 += wr[m][w]     * qq.y + wi[m][w]     * qq.x;
            or1 += wr[m][w + 1] * qq.z - wi[m][w + 1] * qq.w;
            oi1 += wr[m][w + 1] * qq.w + wi[m][w + 1] * qq.z;
        }
    }

    // ---- loss terms ----
    const float ao0 = sqrtf(or0 * or0 + oi0 * oi0);
    const float ao1 = sqrtf(or1 * or1 + oi1 * oi1);
    const float a00 = sqrtf(t0r[0] * t0r[0] + t0i[0] * t0i[0]);
    const float a01 = sqrtf(t0r[1] * t0r[1] + t0i[1] * t0i[1]);
    const float a10 = sqrtf(t1r[0] * t1r[0] + t1i[0] * t1i[0]);
    const float a11 = sqrtf(t1r[1] * t1r[1] + t1i[1] * t1i[1]);

    float L0 = fabsf(t0r[0] - or0) + fabsf(t0i[0] - oi0) + fabsf(a00 - ao0)
             + fabsf(t0r[1] - or1) + fabsf(t0i[1] - oi1) + fabsf(a01 - ao1);
    float L1 = fabsf(t1r[0] - or0) + fabsf(t1i[0] - oi0) + fabsf(a10 - ao0)
             + fabsf(t1r[1] - or1) + fabsf(t1i[1] - oi1) + fabsf(a11 - ao1);
    L0 *= vf;
    L1 *= vf;

    // wave(64) shuffle reduction
    #pragma unroll
    for (int off = 32; off > 0; off >>= 1) {
        L0 += __shfl_down(L0, off, 64);
        L1 += __shfl_down(L1, off, 64);
    }
    __shared__ float s0[4], s1[4];
    if (lane == 0) { s0[wave] = L0; s1[wave] = L1; }
    __syncthreads();
    if (threadIdx.x == 0) {
        const int slot = blockIdx.y * NBLK_X + blockIdx.x;
        ws[slot * 2 + 0] = s0[0] + s0[1] + s0[2] + s0[3];
        ws[slot * 2 + 1] = s1[0] + s1[1] + s1[2] + s1[3];
    }
}

// One block, 256 threads: reduce NSLOT x 2 partials into L[so][st][b],
// then permutation-min. Kernel-boundary dependency makes partials coherent.
__global__ __launch_bounds__(256) void pit_final_kernel(
    const float* __restrict__ ws, float* __restrict__ out, int num_utts)
{
    float acc[16];                       // [so][st][b] = (so*2+st)*4+b
    #pragma unroll
    for (int i = 0; i < 16; ++i) acc[i] = 0.0f;

    for (int slot = threadIdx.x; slot < NSLOT; slot += 256) {
        const int y  = slot / NBLK_X;    // blockIdx.y of producer
        const int sb = y >> 2;
        const int so = sb >> 2;
        const int b  = sb & 3;
        acc[((so * 2 + 0) << 2) + b] += ws[slot * 2 + 0];
        acc[((so * 2 + 1) << 2) + b] += ws[slot * 2 + 1];
    }

    __shared__ float red[16][4];
    const int wave = threadIdx.x >> 6;
    const int lane = threadIdx.x & 63;
    #pragma unroll
    for (int i = 0; i < 16; ++i) {
        float v = acc[i];
        #pragma unroll
        for (int off = 32; off > 0; off >>= 1) v += __shfl_down(v, off, 64);
        if (lane == 0) red[i][wave] = v;
    }
    __syncthreads();

    if (threadIdx.x == 0) {
        float L[16];
        #pragma unroll
        for (int i = 0; i < 16; ++i) L[i] = red[i][0] + red[i][1] + red[i][2] + red[i][3];
        float accu = 0.0f;
        for (int b = 0; b < B_BATCH; ++b) {
            // perm (0,1): L[0][0]+L[1][1];  perm (1,0): L[0][1]+L[1][0]
            const float pid = L[(0 * 2 + 0) * 4 + b] + L[(1 * 2 + 1) * 4 + b];
            const float psw = L[(0 * 2 + 1) * 4 + b] + L[(1 * 2 + 0) * 4 + b];
            const float sc0 = 3.0f * pid / (float)S_SPK;
            const float sc1 = 3.0f * psw / (float)S_SPK;
            accu += fminf(sc0, sc1);
        }
        out[0] = accu / (float)num_utts;
    }
}

extern "C" void kernel_launch(void* const* d_in, const int* in_sizes, int n_in,
                              void* d_out, int out_size, void* d_ws, size_t ws_size,
                              hipStream_t stream) {
    const float* masks = (const float*)d_in[0];
    const float* mixr  = (const float*)d_in[1];
    const float* mixi  = (const float*)d_in[2];
    const float* tgtr  = (const float*)d_in[3];
    const float* tgti  = (const float*)d_in[4];
    // input_sizes values are never used by the reference; only its length is.
    const int num_utts = in_sizes[5];

    float* ws  = (float*)d_ws;
    float* out = (float*)d_out;

    dim3 grid(NBLK_X, NBLK_Y);   // (65, 32)
    pit_main_kernel<<<grid, 256, 0, stream>>>(masks, mixr, mixi, tgtr, tgti, ws);

    pit_final_kernel<<<1, 256, 0, stream>>>(ws, out, num_utts);
}